// Round 13
// baseline (343.489 us; speedup 1.0000x reference)
//
#include <hip/hip_runtime.h>
#include <hip/hip_bf16.h>

#define NN 32768
#define NE 262144

typedef unsigned short u16;
typedef unsigned int   u32;
typedef __bf16 bf16x8 __attribute__((ext_vector_type(8)));
typedef float  f32x16 __attribute__((ext_vector_type(16)));

__device__ __forceinline__ float bf2f(u16 u){ return __uint_as_float(((u32)u)<<16); }
__device__ __forceinline__ u16 f2bf(float f){ __hip_bfloat16 h = __float2bfloat16(f); return *(u16*)&h; }
__device__ __forceinline__ float4 ldbf4(const u16* p){
  ushort4 u = *(const ushort4*)p;
  return make_float4(bf2f(u.x), bf2f(u.y), bf2f(u.z), bf2f(u.w));
}
__device__ __forceinline__ void gload16(const void* g, void* l){
  __builtin_amdgcn_global_load_lds(
      (const __attribute__((address_space(1))) void*)g,
      (__attribute__((address_space(3))) void*)l, 16, 0, 0);
}

// ---------------- CSR build ----------------
__global__ void k_deg(const int* __restrict__ ei, int* deg){
  int e = blockIdx.x*256 + threadIdx.x;
  if (e < NE) atomicAdd(&deg[ei[NE + e]], 1);
}

// blocks 0..127: scan1 ; blocks 128..255: hist
__global__ void k_scan1hist(const int* __restrict__ deg, int* __restrict__ rowptr,
                            int* __restrict__ bsum, int* ghist){
  __shared__ int sbuf[64];
  const int t = threadIdx.x;
  if (blockIdx.x < 128){
    const int b = blockIdx.x;
    const int i = b*256 + t;
    const int ln = t & 63, wv = t >> 6;
    int v = deg[i];
    #pragma unroll
    for (int d = 1; d < 64; d <<= 1){
      int u = __shfl_up(v, d, 64);
      if (ln >= d) v += u;
    }
    if (ln == 63) sbuf[wv] = v;
    __syncthreads();
    int p = 0;
    #pragma unroll
    for (int w = 0; w < 4; w++) if (w < wv) p += sbuf[w];
    v += p;
    rowptr[i + 1] = v;
    if (t == 255) bsum[b] = v;
  } else {
    const int b = blockIdx.x - 128;
    if (t < 64) sbuf[t] = 0;
    __syncthreads();
    int dg = min(deg[b*256 + t], 63);
    atomicAdd(&sbuf[dg], 1);
    __syncthreads();
    if (t < 64 && sbuf[t]) atomicAdd(&ghist[t], sbuf[t]);
  }
}

// block 0: scan2 (128 thr) ; block 1: hoff (64 thr active)
__global__ void k_scan2hoff(const int* __restrict__ bsum, int* __restrict__ boff,
                            const int* __restrict__ ghist, int* __restrict__ goff){
  const int t = threadIdx.x;
  if (blockIdx.x == 0){
    const int ln = t & 63, wv = t >> 6;
    int own = bsum[t];
    int v = own;
    #pragma unroll
    for (int d = 1; d < 64; d <<= 1){
      int u = __shfl_up(v, d, 64);
      if (ln >= d) v += u;
    }
    __shared__ int wsum[2];
    if (ln == 63) wsum[wv] = v;
    __syncthreads();
    if (wv == 1) v += wsum[0];
    boff[t] = v - own;
  } else if (t < 64){
    int v = ghist[t];
    int s = v;
    #pragma unroll
    for (int d = 1; d < 64; d <<= 1){
      int u = __shfl_up(s, d, 64);
      if (t >= d) s += u;
    }
    goff[t] = s - v;
  }
}

// blocks 0..127: scan3 ; blocks 128..255: scatter
__global__ void k_scan3scatter(int* __restrict__ rowptr, const int* __restrict__ boff,
                               const int* __restrict__ deg, const int* __restrict__ goff,
                               int* gcur, int* __restrict__ perm){
  const int t = threadIdx.x;
  if (blockIdx.x < 128){
    const int b = blockIdx.x;
    rowptr[1 + b*256 + t] += boff[b];
    if (b == 0 && t == 0) rowptr[0] = 0;
  } else {
    __shared__ int lh[64], lbase[64];
    const int b = blockIdx.x - 128;
    if (t < 64) lh[t] = 0;
    __syncthreads();
    const int n = b*256 + t;
    const int dg = min(deg[n], 63);
    int lrank = atomicAdd(&lh[dg], 1);
    __syncthreads();
    if (t < 64) lbase[t] = lh[t] ? atomicAdd(&gcur[t], lh[t]) : 0;
    __syncthreads();
    perm[goff[dg] + lbase[dg] + lrank] = n;
  }
}

// fill CSR: csrc + CSR-sorted edge attrs
__global__ void k_fill(const int* __restrict__ ei, const int* __restrict__ rowptr,
                       int* cursor, const float* __restrict__ ea,
                       int* __restrict__ csrc, float4* __restrict__ ea_csr){
  int e = blockIdx.x*256 + threadIdx.x;
  if (e < NE){
    int d = ei[NE + e];
    int p = rowptr[d] + atomicAdd(&cursor[d], 1);
    csrc[p] = ei[e];
    float4 a = *(const float4*)&ea[(size_t)e*8];
    float4 b = *(const float4*)&ea[(size_t)e*8 + 4];
    ea_csr[(size_t)p*2]     = a;
    ea_csr[(size_t)p*2 + 1] = b;
  }
}

// ---------------- fused weight prep: wprep(0..199) + mprep_l0(200..215) + mprep_l1(216..247) + eprep(248..258) ----------------
struct WPtrs { const float* w[8]; const float* b[8]; };

__device__ void mprep_body(const float* __restrict__ Wq, const float* __restrict__ bq,
                           const float* __restrict__ We, __bf16* __restrict__ Wcat,
                           float* __restrict__ bcat, int kb,
                           float* sWq, float* sWe2){
  const int t = threadIdx.x;
  for (int i = t; i < 2048; i += 256){
    sWq[i]  = Wq[(size_t)(kb*8 + (i>>8))*256 + (i & 255)];
    sWe2[i] = We[i];
  }
  __syncthreads();
  const int kk = t >> 5, col = t & 31;
  const int h = col >> 3, i = col & 7;
  float a = 0.f;
  #pragma unroll 8
  for (int c = 0; c < 64; c++)
    a += sWq[kk*256 + h*64 + c]*sWe2[i*256 + h*64 + c];
  int k = kb*8 + kk;
  int q = (k >> 4)*2 + ((k >> 3) & 1), j = k & 7;
  Wcat[((size_t)q*1152 + 1024 + col)*8 + j] = (__bf16)(0.125f*a);
  for (int z = t; z < 768; z += 256){
    int kz = kb*8 + (z / 96), cz = 32 + (z % 96);
    int qz = (kz >> 4)*2 + ((kz >> 3) & 1), jz = kz & 7;
    Wcat[((size_t)qz*1152 + 1024 + cz)*8 + jz] = (__bf16)0.f;
  }
  if (kb == 0 && t < 32){
    int hh = t >> 3, ii = t & 7;
    float b = 0.f;
    for (int c = 0; c < 64; c++) b += bq[hh*64 + c]*sWe2[ii*256 + hh*64 + c];
    bcat[1024 + t] = 0.125f*b;
  }
}

__global__ void k_prep(WPtrs wp, __bf16* __restrict__ W0cat, __bf16* __restrict__ W1cat,
                       float* __restrict__ bcat0, float* __restrict__ bcat1,
                       const float* __restrict__ Wq0, const float* __restrict__ bq0,
                       const float* __restrict__ We0,
                       const float* __restrict__ Wq1, const float* __restrict__ bq1,
                       const float* __restrict__ We1,
                       const float* __restrict__ eW1, const float* __restrict__ eb1,
                       const float* __restrict__ eW2, const float* __restrict__ eg1,
                       const float* __restrict__ eb2, const float* __restrict__ ebe1,
                       __bf16* __restrict__ Ecat){
  __shared__ float sWq[2048], sWe2[2048];
  const int b = blockIdx.x, t = threadIdx.x;
  if (b < 200){
    int gid = b*256 + t;
    if (gid < 16384){
      int mat = gid >> 12, v = gid & 4095;
      int colm = v & 255, q = v >> 8;
      int k0 = (q>>1)*16 + (q&1)*8;
      const float* W = wp.w[mat];
      bf16x8 vec;
      #pragma unroll
      for (int j = 0; j < 8; j++) vec[j] = (__bf16)W[(size_t)(k0+j)*256 + colm];
      *(bf16x8*)&W0cat[((size_t)q*1152 + mat*256 + colm)*8] = vec;
    } else if (gid < 49152){
      int g = gid - 16384;
      int mat = g >> 13, v = g & 8191;
      int colm = v & 255, q = v >> 8;
      int k0 = (q>>1)*16 + (q&1)*8;
      const float* W = wp.w[4+mat];
      bf16x8 vec;
      #pragma unroll
      for (int j = 0; j < 8; j++) vec[j] = (__bf16)W[(size_t)(k0+j)*256 + colm];
      *(bf16x8*)&W1cat[((size_t)q*1152 + mat*256 + colm)*8] = vec;
    } else if (gid < 51200){
      int g = gid - 49152;
      if (g < 1024) bcat0[g] = wp.b[g>>8][g&255];
      else { int h = g-1024; bcat1[h] = wp.b[4 + (h>>8)][h&255]; }
    }
  } else if (b < 216){
    mprep_body(Wq0, bq0, We0, W0cat, bcat0, b - 200, sWq, sWe2);
  } else if (b < 248){
    mprep_body(Wq1, bq1, We1, W1cat, bcat1, b - 216, sWq, sWe2);
  } else {
    int i = (b - 248)*256 + t;
    if (i >= 2816) return;
    bf16x8 v;
    if (i < 512){
      int r = i & 31, hh = (i>>5)&1, ks = (i>>6)&1, rt = i>>7;
      int feat = rt*32 + r, k0 = ks*16 + hh*8;
      #pragma unroll
      for (int j = 0; j < 8; j++){
        int k = k0 + j;
        float val = (k < 24) ? eW1[k*128 + feat] : ((k == 24) ? eb1[feat] : 0.f);
        v[j] = (__bf16)val;
      }
    } else {
      int m = i - 512;
      int r = m & 31, hh = (m>>5)&1, q = m>>6;
      int ks = q % 9, rt = q / 9;
      int feat = rt*32 + r, k0 = ks*16 + hh*8;
      #pragma unroll
      for (int j = 0; j < 8; j++){
        int k = k0 + j;
        float val;
        if (k < 128) val = eg1[k]*eW2[k*128 + feat];
        else if (k == 128){           // inline b2p[feat]
          float a = eb2[feat];
          for (int kk = 0; kk < 128; kk++) a += ebe1[kk]*eW2[kk*128 + feat];
          val = a;
        } else val = 0.f;
        v[j] = (__bf16)val;
      }
    }
    *(bf16x8*)&Ecat[(size_t)i*8] = v;
  }
}

// ---------------- EmbedConv v7: edge-split (2 waves/window), 2 blocks/CU ----------------
__global__ __launch_bounds__(256, 1) void k_embed(
    const float* __restrict__ x, const float4* __restrict__ ea_csr,
    const int* __restrict__ csrc, const int* __restrict__ rowptr,
    const int* __restrict__ perm, const __bf16* __restrict__ Ecat,
    const float* __restrict__ g2, const float* __restrict__ be2,
    u16* __restrict__ h0b)
{
  __shared__ alignas(16) __bf16 sE[2816*8];   // 45 KB (reused post-loop as f32 exchange)
  __shared__ float sg2[128], sbe2[128];
  const int t = threadIdx.x;
  const int wv = t >> 6, ln = t & 63, hi = ln >> 5, c32 = ln & 31;

  #pragma unroll
  for (int k = 0; k < 11; k++){
    int base = k*256 + wv*64;
    gload16(Ecat + (size_t)(base + ln)*8, &sE[(size_t)base*8]);
  }
  if (t < 128){ sg2[t] = g2[t]; sbe2[t] = be2[t]; }
  asm volatile("s_waitcnt vmcnt(0)" ::: "memory");
  __syncthreads();

  const int win  = blockIdx.x + (wv >> 1)*512;
  const int half = wv & 1;
  const int d    = perm[win*32 + c32];
  const int rp   = rowptr[d];
  const int deg  = rowptr[d+1] - rp;
  int md = deg;
  #pragma unroll
  for (int m = 1; m < 32; m <<= 1) md = max(md, __shfl_xor(md, m, 32));

  f32x16 hacc[4] = {};

  bool vc = half < deg;
  int p0 = vc ? (rp + half) : rp;
  int sc = csrc[p0];
  float4 xa = *(const float4*)&x[(size_t)sc*16 + hi*8];
  float4 xb = *(const float4*)&x[(size_t)sc*16 + hi*8 + 4];
  float4 ga = ea_csr[(size_t)p0*2];
  float4 gb = ea_csr[(size_t)p0*2 + 1];

  for (int j = half; j < md; j += 2){
    const float vm = vc ? 1.f : 0.f;
    bf16x8 b1f0, b1f1;
    {
      float xv[8]; *(float4*)&xv[0] = xa; *(float4*)&xv[4] = xb;
      #pragma unroll
      for (int q = 0; q < 8; q++) b1f0[q] = (__bf16)(xv[q]*vm);
      float evv[8]; *(float4*)&evv[0] = ga; *(float4*)&evv[4] = gb;
      #pragma unroll
      for (int q = 0; q < 8; q++)
        b1f1[q] = (__bf16)(hi ? ((q == 0) ? vm : 0.f) : evv[q]*vm);
    }

    bool vn = (j + 2) < deg;
    int pn = vn ? (rp + j + 2) : rp;
    int sn = csrc[pn];
    float4 xan = *(const float4*)&x[(size_t)sn*16 + hi*8];
    float4 xbn = *(const float4*)&x[(size_t)sn*16 + hi*8 + 4];
    float4 gan = ea_csr[(size_t)pn*2];
    float4 gbn = ea_csr[(size_t)pn*2 + 1];

    f32x16 a1[4] = {};
    #pragma unroll
    for (int ks = 0; ks < 2; ks++)
      #pragma unroll
      for (int rt = 0; rt < 4; rt++){
        bf16x8 af = *(const bf16x8*)&sE[((((rt*2 + ks)*2 + hi)*32) + c32)*8];
        a1[rt] = __builtin_amdgcn_mfma_f32_32x32x16_bf16(af, ks ? b1f1 : b1f0, a1[rt], 0, 0, 0);
      }

    {
      float s1 = 0.f, s2 = 0.f;
      #pragma unroll
      for (int rt = 0; rt < 4; rt++)
        #pragma unroll
        for (int rg = 0; rg < 16; rg++){
          float v = fmaxf(a1[rt][rg], 0.f);
          a1[rt][rg] = v; s1 += v; s2 += v*v;
        }
      s1 += __shfl_xor(s1, 32, 64);
      s2 += __shfl_xor(s2, 32, 64);
      float mean = s1*(1.f/128.f);
      float rs = rsqrtf(s2*(1.f/128.f) - mean*mean + 1e-5f);
      #pragma unroll
      for (int rt = 0; rt < 4; rt++)
        #pragma unroll
        for (int rg = 0; rg < 16; rg++)
          a1[rt][rg] = (a1[rt][rg] - mean)*rs;
    }

    f32x16 a2[4] = {};
    #pragma unroll
    for (int ks = 0; ks < 8; ks++){
      const int tt = ks >> 1, bb = (ks & 1)*8;
      float snd[4], rcv[4];
      #pragma unroll
      for (int q = 0; q < 4; q++)
        snd[q] = hi ? a1[tt][bb + q] : a1[tt][bb + 4 + q];
      #pragma unroll
      for (int q = 0; q < 4; q++)
        rcv[q] = __shfl_xor(snd[q], 32, 64);
      bf16x8 bf;
      #pragma unroll
      for (int q = 0; q < 4; q++){
        float lo = hi ? rcv[q] : a1[tt][bb + q];
        float hh = hi ? a1[tt][bb + 4 + q] : rcv[q];
        bf[q]     = (__bf16)lo;
        bf[4 + q] = (__bf16)hh;
      }
      #pragma unroll
      for (int rt = 0; rt < 4; rt++){
        bf16x8 af = *(const bf16x8*)&sE[(512 + (((rt*9 + ks)*2 + hi)*32) + c32)*8];
        a2[rt] = __builtin_amdgcn_mfma_f32_32x32x16_bf16(af, bf, a2[rt], 0, 0, 0);
      }
    }
    {
      bf16x8 bf;
      #pragma unroll
      for (int q = 0; q < 8; q++)
        bf[q] = (__bf16)((!hi && q == 0) ? vm : 0.f);
      #pragma unroll
      for (int rt = 0; rt < 4; rt++){
        bf16x8 af = *(const bf16x8*)&sE[(512 + (((rt*9 + 8)*2 + hi)*32) + c32)*8];
        a2[rt] = __builtin_amdgcn_mfma_f32_32x32x16_bf16(af, bf, a2[rt], 0, 0, 0);
      }
    }

    {
      float s1 = 0.f, s2 = 0.f;
      #pragma unroll
      for (int rt = 0; rt < 4; rt++)
        #pragma unroll
        for (int rg = 0; rg < 16; rg++){
          float v = fmaxf(a2[rt][rg], 0.f);
          a2[rt][rg] = v; s1 += v; s2 += v*v;
        }
      s1 += __shfl_xor(s1, 32, 64);
      s2 += __shfl_xor(s2, 32, 64);
      float mean = s1*(1.f/128.f);
      float rs = rsqrtf(s2*(1.f/128.f) - mean*mean + 1e-5f);
      #pragma unroll
      for (int rt = 0; rt < 4; rt++)
        #pragma unroll
        for (int rg = 0; rg < 16; rg++)
          hacc[rt][rg] += (a2[rt][rg] - mean)*rs;
    }

    vc = vn;
    xa = xan; xb = xbn; ga = gan; gb = gbn;
  }

  __syncthreads();
  float* xch = (float*)sE;
  const int wbase = (wv >> 1)*(64*65);
  if (!half){
    #pragma unroll
    for (int rt = 0; rt < 4; rt++)
      #pragma unroll
      for (int rg = 0; rg < 16; rg++)
        xch[wbase + (rt*16 + rg)*65 + ln] = hacc[rt][rg];
  }
  __syncthreads();
  if (half){
    const float dd = (float)deg;
    #pragma unroll
    for (int rt = 0; rt < 4; rt++){
      #pragma unroll
      for (int rg = 0; rg < 16; rg++)
        hacc[rt][rg] += xch[wbase + (rt*16 + rg)*65 + ln];
      #pragma unroll
      for (int q = 0; q < 4; q++){
        int fb = rt*32 + 8*q + 4*hi;
        ushort4 o;
        o.x = f2bf(sg2[fb+0]*hacc[rt][q*4+0] + dd*sbe2[fb+0]);
        o.y = f2bf(sg2[fb+1]*hacc[rt][q*4+1] + dd*sbe2[fb+1]);
        o.z = f2bf(sg2[fb+2]*hacc[rt][q*4+2] + dd*sbe2[fb+2]);
        o.w = f2bf(sg2[fb+3]*hacc[rt][q*4+3] + dd*sbe2[fb+3]);
        *(ushort4*)&h0b[(size_t)d*128 + fb] = o;
      }
    }
  }
}

// ---------------- qkvs GEMM v4: single-buffer, 9 col-tiles (q,k,v,s,wqe), fused kv ----------------
template<int K>
__global__ __launch_bounds__(256) void k_qkvs2(const u16* __restrict__ A,
    const __bf16* __restrict__ Wcat, const float* __restrict__ bcat,
    u16* __restrict__ qo, u16* __restrict__ kvb, u16* __restrict__ so,
    u16* __restrict__ wqe)
{
  __shared__ alignas(16) __bf16 sA[1024*8];   // 16 KB
  __shared__ alignas(16) __bf16 sB[1024*8];   // 16 KB
  const int t = threadIdx.x;
  const int swz = (blockIdx.x & 7)*288 + (blockIdx.x >> 3);   // 2304 blocks, 8 XCDs
  const int r0 = (swz / 9)*128, c0 = (swz % 9)*128;
  const int wv = t >> 6, ln = t & 63, hi = ln >> 5, c32 = ln & 31;
  const int wr = wv >> 1, wc = wv & 1;

  f32x16 acc[2][2] = {};
  for (int kc = 0; kc < K/64; kc++){
    __syncthreads();
    #pragma unroll
    for (int ii = 0; ii < 4; ii++){
      int v = ii*256 + wv*64 + ln;
      int r = v & 31, hh = (v>>5)&1, ks = (v>>6)&3, rt = v>>8;
      gload16(A + (size_t)(r0 + rt*32 + r)*K + kc*64 + ks*16 + hh*8,
              &sA[(size_t)(ii*256 + wv*64)*8]);
    }
    #pragma unroll
    for (int ii = 0; ii < 4; ii++){
      int v = ii*256 + wv*64 + ln;
      int col = v & 127, q = v >> 7;
      gload16(Wcat + ((size_t)(kc*8 + q)*1152 + c0 + col)*8,
              &sB[(size_t)(ii*256 + wv*64)*8]);
    }
    asm volatile("s_waitcnt vmcnt(0)" ::: "memory");
    __syncthreads();
    #pragma unroll
    for (int ks = 0; ks < 4; ks++){
      bf16x8 af0 = *(const bf16x8*)&sA[((((wr*2+0)*4 + ks)*2 + hi)*32 + c32)*8];
      bf16x8 af1 = *(const bf16x8*)&sA[((((wr*2+1)*4 + ks)*2 + hi)*32 + c32)*8];
      bf16x8 bf0 = *(const bf16x8*)&sB[(((ks*2 + hi)*128) + wc*64 + c32)*8];
      bf16x8 bf1 = *(const bf16x8*)&sB[(((ks*2 + hi)*128) + wc*64 + 32 + c32)*8];
      acc[0][0] = __builtin_amdgcn_mfma_f32_32x32x16_bf16(af0, bf0, acc[0][0], 0, 0, 0);
      acc[0][1] = __builtin_amdgcn_mfma_f32_32x32x16_bf16(af0, bf1, acc[0][1], 0, 0, 0);
      acc[1][0] = __builtin_amdgcn_mfma_f32_32x32x16_bf16(af1, bf0, acc[1][0], 0, 0, 0);
      acc[1][1] = __builtin_amdgcn_mfma_f32_32x32x16_bf16(af1, bf1, acc[1][1], 0, 0, 0);
    }
  }

  const int tile = c0 >> 7;
  u16* omp; int rstride; int vadd = -1; bool wq8 = false;
  if (tile < 2)      { omp = qo;  rstride = 256; }
  else if (tile < 4) { omp = kvb; rstride = 512; vadd = 0; }
  else if (tile < 6) { omp = kvb; rstride = 512; vadd = 4; }
  else if (tile < 8) { omp = so;  rstride = 256; }
  else               { omp = wqe; rstride = 32; wq8 = true; }
  const int cb = c0 & 255;
  #pragma unroll
  for (int ci = 0; ci < 2; ci++){
    int colm = (wq8 ? 0 : cb) + wc*64 + ci*32 + c32;
    int coff = (vadd >= 0) ? (((colm >> 2) << 3) + vadd + (colm & 3)) : colm;
    float bb = bcat[c0 + wc*64 + ci*32 + c32];
    if (wq8 && colm >= 32) continue;
    #pragma unroll
    for (int ri = 0; ri < 2; ri++){
      #pragma unroll
      for (int rg = 0; rg < 16; rg++){
        int row = r0 + (wr*2 + ri)*32 + (rg&3) + 8*(rg>>2) + 4*hi;
        omp[(size_t)row*rstride + coff] = f2bf(acc[ri][ci][rg] + bb);
      }
    }
  }
}

// ---------------- TransformerConv attention v6: fused kv, 6-deep pipeline, precomputed wqe ----------------
template<bool OBF>
__global__ __launch_bounds__(256) void k_attn(
    const int* __restrict__ csrc, const int* __restrict__ rowptr,
    const float4* __restrict__ ea_csr, const float* __restrict__ We,
    const u16* __restrict__ qb, const u16* __restrict__ kvb,
    const u16* __restrict__ skb, const u16* __restrict__ wqe,
    void* __restrict__ outp)
{
  __shared__ float sWe[8*256];
  const int t = threadIdx.x;
  for (int i = t; i < 2048; i += 256) sWe[i] = We[i];
  __syncthreads();

  const float* eaf = (const float*)ea_csr;
  const int wv = t >> 6, ln = t & 63;
  const int f = (ln >> 4)*64 + (ln & 15)*4;
  const int kvo = ((ln >> 4)*16 + (ln & 15))*8;
  const int iown = ln & 7;
  const int gbase = ln & ~15;
  const int gw = blockIdx.x*4 + wv, nW = gridDim.x*4;

#define ATT_PRE(RX, EX, jj) do{                                            \
      int sj_ = ((jj) < 64) ? __shfl(sidx, (jj), 64) : csrc[rp + (jj)];    \
      RX = *(const int4*)&kvb[(size_t)sj_*512 + kvo];                      \
      EX = eaf[(size_t)(rp + (jj))*8 + iown];                              \
    }while(0)

#define ATT_STEP(RX, EX) do{                                               \
      float kx0 = bf2f((u16)(RX.x & 0xffff)), kx1 = bf2f((u16)(((u32)RX.x)>>16)); \
      float kx2 = bf2f((u16)(RX.y & 0xffff)), kx3 = bf2f((u16)(((u32)RX.y)>>16)); \
      float vx0 = bf2f((u16)(RX.z & 0xffff)), vx1 = bf2f((u16)(((u32)RX.z)>>16)); \
      float vx2 = bf2f((u16)(RX.w & 0xffff)), vx3 = bf2f((u16)(((u32)RX.w)>>16)); \
      float spp = qv.x*kx0 + qv.y*kx1 + qv.z*kx2 + qv.w*kx3 + EX*wqsel;    \
      spp += __shfl_xor(spp, 1, 64); spp += __shfl_xor(spp, 2, 64);        \
      spp += __shfl_xor(spp, 4, 64); spp += __shfl_xor(spp, 8, 64);        \
      float nm = fmaxf(m, spp);                                            \
      float sc_ = __expf(m - nm);                                          \
      float pp = __expf(spp - nm);                                         \
      l = l*sc_ + pp;                                                      \
      o0 = o0*sc_ + pp*vx0; o1 = o1*sc_ + pp*vx1;                          \
      o2 = o2*sc_ + pp*vx2; o3 = o3*sc_ + pp*vx3;                          \
      weal = weal*sc_ + pp*EX;                                             \
      m = nm;                                                              \
    }while(0)

  for (int d = gw; d < NN; d += nW){
    const int rp = rowptr[d];
    const int dg = rowptr[d+1] - rp;
    float4 qv = ldbf4(qb + (size_t)d*256 + f);
    qv.x *= 0.125f; qv.y *= 0.125f; qv.z *= 0.125f; qv.w *= 0.125f;
    float4 sv = ldbf4(skb + (size_t)d*256 + f);

    float wqsel = ((ln & 15) < 8)
                ? bf2f(wqe[(size_t)d*32 + (ln >> 4)*8 + (ln & 7)]) : 0.f;

    float m = -INFINITY, l = 0.f, o0 = 0, o1 = 0, o2 = 0, o3 = 0, weal = 0.f;

    if (dg > 0){
      int sidx = (ln < dg) ? csrc[rp + ln] : 0;
      int4 rA, rB, rC, rD, rE, rF; float eA, eB, eC, eD, eE, eF;
      ATT_PRE(rA, eA, 0);
      if (dg > 1) ATT_PRE(rB, eB, 1);
      if (dg > 2) ATT_PRE(rC, eC, 2);
      if (dg > 3) ATT_PRE(rD, eD, 3);
      if (dg > 4) ATT_PRE(rE, eE, 4);
      if (dg > 5) ATT_PRE(rF, eF, 5);

      int j = 0;
      while (j < dg){
        ATT_STEP(rA, eA); if (j + 6 < dg) ATT_PRE(rA, eA, j + 6); if (++j >= dg) break;
        ATT_STEP(rB, eB); if (j + 6 < dg) ATT_PRE(rB, eB, j + 6); if (++j >= dg) break;
        ATT_STEP(rC, eC); if (j + 6 < dg) ATT_PRE(rC, eC, j + 6); if (++j >= dg) break;
        ATT_STEP(rD, eD); if (j + 6 < dg) ATT_PRE(rD, eD, j + 6); if (++j >= dg) break;
        ATT_STEP(rE, eE); if (j + 6 < dg) ATT_PRE(rE, eE, j + 6); if (++j >= dg) break;
        ATT_STEP(rF, eF); if (j + 6 < dg) ATT_PRE(rF, eF, j + 6); ++j;
      }
    }

    float il = (l > 0.f) ? 1.f/l : 0.f;
    float ec0 = 0, ec1 = 0, ec2 = 0, ec3 = 0;
    #pragma unroll
    for (int i = 0; i < 8; i++){
      float wi = __shfl(weal, gbase + i, 64);
      float4 w = *(const float4*)&sWe[i*256 + f];
      ec0 += wi*w.x; ec1 += wi*w.y; ec2 += wi*w.z; ec3 += wi*w.w;
    }
    o0 = fmaxf((o0 + ec0)*il + sv.x, 0.f);
    o1 = fmaxf((o1 + ec1)*il + sv.y, 0.f);
    o2 = fmaxf((o2 + ec2)*il + sv.z, 0.f);
    o3 = fmaxf((o3 + ec3)*il + sv.w, 0.f);
    if constexpr (OBF){
      ushort4 o; o.x = f2bf(o0); o.y = f2bf(o1); o.z = f2bf(o2); o.w = f2bf(o3);
      *(ushort4*)((u16*)outp + (size_t)d*256 + f) = o;
    } else {
      *(float4*)((float*)outp + (size_t)d*256 + f) = make_float4(o0, o1, o2, o3);
    }
  }
#undef ATT_PRE
#undef ATT_STEP
}

extern "C" void kernel_launch(void* const* d_in, const int* in_sizes, int n_in,
                              void* d_out, int out_size, void* d_ws, size_t ws_size,
                              hipStream_t stream)
{
  (void)in_sizes; (void)n_in; (void)out_size; (void)ws_size;
  const float* x   = (const float*)d_in[0];
  const int*   ei  = (const int*)  d_in[1];
  const float* ea  = (const float*)d_in[2];
  const float* eW1 = (const float*)d_in[3];
  const float* eb1 = (const float*)d_in[4];
  const float* eg1 = (const float*)d_in[5];
  const float* ebe1= (const float*)d_in[6];
  const float* eW2 = (const float*)d_in[7];
  const float* eb2 = (const float*)d_in[8];
  const float* eg2 = (const float*)d_in[9];
  const float* ebe2= (const float*)d_in[10];

  char* ws = (char*)d_ws;
  const size_t MB = (size_t)1 << 20;
  const size_t KB = (size_t)1 << 10;
  int*   deg    = (int*)(ws);                  // 0..128K
  int*   cursor = (int*)(ws + 128*KB);         // 128..256K
  int*   rowptr = (int*)(ws + 256*KB);         // 256..384K+4
  int*   bsum   = (int*)(ws + 400*KB);
  int*   boff   = (int*)(ws + 402*KB);
  int*   ghist  = (int*)(ws + 408*KB);
  int*   gcur   = (int*)(ws + 412*KB);
  int*   goff   = (int*)(ws + 416*KB);
  int*   perm   = (int*)(ws + 512*KB);
  int*   csrc   = (int*)(ws + 1*MB);
  float4* ea_csr= (float4*)(ws + 4*MB);
  u16*   qb     = (u16*)(ws + 20*MB);
  u16*   kvb    = (u16*)(ws + 36*MB);
  u16*   skb    = (u16*)(ws + 68*MB);
  u16*   h1     = (u16*)(ws + 84*MB);
  u16*   h0b    = (u16*)(ws + 100*MB);
  __bf16* W0cat = (__bf16*)(ws + 108*MB);
  __bf16* W1cat = (__bf16*)(ws + 109*MB);
  float* bcat0  = (float*)(ws + 110*MB);
  float* bcat1  = (float*)(ws + 110*MB + 64*KB);
  __bf16* Ecat  = (__bf16*)(ws + 111*MB);
  u16*   wqeb   = (u16*)(ws + 112*MB);

  hipMemsetAsync(ws, 0, 420*KB, stream);   // deg+cursor+rowptr0+bsum+boff+ghist+gcur+goff

  WPtrs wp;
  wp.w[0] = (const float*)d_in[11]; wp.b[0] = (const float*)d_in[12];
  wp.w[1] = (const float*)d_in[13]; wp.b[1] = (const float*)d_in[14];
  wp.w[2] = (const float*)d_in[15]; wp.b[2] = (const float*)d_in[16];
  wp.w[3] = (const float*)d_in[18]; wp.b[3] = (const float*)d_in[19];
  wp.w[4] = (const float*)d_in[20]; wp.b[4] = (const float*)d_in[21];
  wp.w[5] = (const float*)d_in[22]; wp.b[5] = (const float*)d_in[23];
  wp.w[6] = (const float*)d_in[24]; wp.b[6] = (const float*)d_in[25];
  wp.w[7] = (const float*)d_in[27]; wp.b[7] = (const float*)d_in[28];

  k_deg        <<<NE/256, 256, 0, stream>>>(ei, deg);
  k_prep       <<<259,    256, 0, stream>>>(wp, W0cat, W1cat, bcat0, bcat1,
                  (const float*)d_in[11], (const float*)d_in[12], (const float*)d_in[17],
                  (const float*)d_in[20], (const float*)d_in[21], (const float*)d_in[26],
                  eW1, eb1, eW2, eg1, eb2, ebe1, Ecat);
  k_scan1hist  <<<256, 256, 0, stream>>>(deg, rowptr, bsum, ghist);
  k_scan2hoff  <<<2,   128, 0, stream>>>(bsum, boff, ghist, goff);
  k_scan3scatter<<<256,256, 0, stream>>>(rowptr, boff, deg, goff, gcur, perm);
  k_fill       <<<NE/256, 256, 0, stream>>>(ei, rowptr, cursor, ea, csrc, ea_csr);

  k_embed<<<512, 256, 0, stream>>>(x, ea_csr, csrc, rowptr, perm, Ecat, eg2, ebe2, h0b);

  // layer 0 (K = 128)
  k_qkvs2<128><<<2304, 256, 0, stream>>>(h0b, W0cat, bcat0, qb, kvb, skb, wqeb);
  k_attn<true><<<NN/4, 256, 0, stream>>>(csrc, rowptr, ea_csr, (const float*)d_in[17],
                                         qb, kvb, skb, wqeb, (void*)h1);
  // layer 1 (K = 256)
  k_qkvs2<256><<<2304, 256, 0, stream>>>(h1, W1cat, bcat1, qb, kvb, skb, wqeb);
  k_attn<false><<<NN/4, 256, 0, stream>>>(csrc, rowptr, ea_csr, (const float*)d_in[26],
                                          qb, kvb, skb, wqeb, d_out);
}

// Round 14
// 314.707 us; speedup vs baseline: 1.0915x; 1.0915x over previous
//
#include <hip/hip_runtime.h>
#include <hip/hip_bf16.h>

#define NN 32768
#define NE 262144

typedef unsigned short u16;
typedef unsigned int   u32;
typedef __bf16 bf16x8 __attribute__((ext_vector_type(8)));
typedef float  f32x16 __attribute__((ext_vector_type(16)));

__device__ __forceinline__ float bf2f(u16 u){ return __uint_as_float(((u32)u)<<16); }
__device__ __forceinline__ u16 f2bf(float f){ __hip_bfloat16 h = __float2bfloat16(f); return *(u16*)&h; }
__device__ __forceinline__ float4 ldbf4(const u16* p){
  ushort4 u = *(const ushort4*)p;
  return make_float4(bf2f(u.x), bf2f(u.y), bf2f(u.z), bf2f(u.w));
}
__device__ __forceinline__ void gload16(const void* g, void* l){
  __builtin_amdgcn_global_load_lds(
      (const __attribute__((address_space(1))) void*)g,
      (__attribute__((address_space(3))) void*)l, 16, 0, 0);
}

// ---------------- CSR build ----------------
__global__ void k_deg(const int* __restrict__ ei, int* deg){
  int e = blockIdx.x*256 + threadIdx.x;
  if (e < NE) atomicAdd(&deg[ei[NE + e]], 1);
}

// blocks 0..127: scan1 ; blocks 128..255: hist
__global__ void k_scan1hist(const int* __restrict__ deg, int* __restrict__ rowptr,
                            int* __restrict__ bsum, int* ghist){
  __shared__ int sbuf[64];
  const int t = threadIdx.x;
  if (blockIdx.x < 128){
    const int b = blockIdx.x;
    const int i = b*256 + t;
    const int ln = t & 63, wv = t >> 6;
    int v = deg[i];
    #pragma unroll
    for (int d = 1; d < 64; d <<= 1){
      int u = __shfl_up(v, d, 64);
      if (ln >= d) v += u;
    }
    if (ln == 63) sbuf[wv] = v;
    __syncthreads();
    int p = 0;
    #pragma unroll
    for (int w = 0; w < 4; w++) if (w < wv) p += sbuf[w];
    v += p;
    rowptr[i + 1] = v;
    if (t == 255) bsum[b] = v;
  } else {
    const int b = blockIdx.x - 128;
    if (t < 64) sbuf[t] = 0;
    __syncthreads();
    int dg = min(deg[b*256 + t], 63);
    atomicAdd(&sbuf[dg], 1);
    __syncthreads();
    if (t < 64 && sbuf[t]) atomicAdd(&ghist[t], sbuf[t]);
  }
}

// block 0: scan2 (128 thr) ; block 1: hoff (64 thr active)
__global__ void k_scan2hoff(const int* __restrict__ bsum, int* __restrict__ boff,
                            const int* __restrict__ ghist, int* __restrict__ goff){
  const int t = threadIdx.x;
  if (blockIdx.x == 0){
    const int ln = t & 63, wv = t >> 6;
    int own = bsum[t];
    int v = own;
    #pragma unroll
    for (int d = 1; d < 64; d <<= 1){
      int u = __shfl_up(v, d, 64);
      if (ln >= d) v += u;
    }
    __shared__ int wsum[2];
    if (ln == 63) wsum[wv] = v;
    __syncthreads();
    if (wv == 1) v += wsum[0];
    boff[t] = v - own;
  } else if (t < 64){
    int v = ghist[t];
    int s = v;
    #pragma unroll
    for (int d = 1; d < 64; d <<= 1){
      int u = __shfl_up(s, d, 64);
      if (t >= d) s += u;
    }
    goff[t] = s - v;
  }
}

// blocks 0..127: scan3 ; blocks 128..255: scatter
__global__ void k_scan3scatter(int* __restrict__ rowptr, const int* __restrict__ boff,
                               const int* __restrict__ deg, const int* __restrict__ goff,
                               int* gcur, int* __restrict__ perm){
  const int t = threadIdx.x;
  if (blockIdx.x < 128){
    const int b = blockIdx.x;
    rowptr[1 + b*256 + t] += boff[b];
    if (b == 0 && t == 0) rowptr[0] = 0;
  } else {
    __shared__ int lh[64], lbase[64];
    const int b = blockIdx.x - 128;
    if (t < 64) lh[t] = 0;
    __syncthreads();
    const int n = b*256 + t;
    const int dg = min(deg[n], 63);
    int lrank = atomicAdd(&lh[dg], 1);
    __syncthreads();
    if (t < 64) lbase[t] = lh[t] ? atomicAdd(&gcur[t], lh[t]) : 0;
    __syncthreads();
    perm[goff[dg] + lbase[dg] + lrank] = n;
  }
}

// fill CSR: csrc + CSR-sorted edge attrs
__global__ void k_fill(const int* __restrict__ ei, const int* __restrict__ rowptr,
                       int* cursor, const float* __restrict__ ea,
                       int* __restrict__ csrc, float4* __restrict__ ea_csr){
  int e = blockIdx.x*256 + threadIdx.x;
  if (e < NE){
    int d = ei[NE + e];
    int p = rowptr[d] + atomicAdd(&cursor[d], 1);
    csrc[p] = ei[e];
    float4 a = *(const float4*)&ea[(size_t)e*8];
    float4 b = *(const float4*)&ea[(size_t)e*8 + 4];
    ea_csr[(size_t)p*2]     = a;
    ea_csr[(size_t)p*2 + 1] = b;
  }
}

// ---------------- fused weight prep ----------------
struct WPtrs { const float* w[8]; const float* b[8]; };

__device__ void mprep_body(const float* __restrict__ Wq, const float* __restrict__ bq,
                           const float* __restrict__ We, __bf16* __restrict__ Wcat,
                           float* __restrict__ bcat, int kb,
                           float* sWq, float* sWe2){
  const int t = threadIdx.x;
  for (int i = t; i < 2048; i += 256){
    sWq[i]  = Wq[(size_t)(kb*8 + (i>>8))*256 + (i & 255)];
    sWe2[i] = We[i];
  }
  __syncthreads();
  const int kk = t >> 5, col = t & 31;
  const int h = col >> 3, i = col & 7;
  float a = 0.f;
  #pragma unroll 8
  for (int c = 0; c < 64; c++)
    a += sWq[kk*256 + h*64 + c]*sWe2[i*256 + h*64 + c];
  int k = kb*8 + kk;
  int q = (k >> 4)*2 + ((k >> 3) & 1), j = k & 7;
  Wcat[((size_t)q*1152 + 1024 + col)*8 + j] = (__bf16)(0.125f*a);
  for (int z = t; z < 768; z += 256){
    int kz = kb*8 + (z / 96), cz = 32 + (z % 96);
    int qz = (kz >> 4)*2 + ((kz >> 3) & 1), jz = kz & 7;
    Wcat[((size_t)qz*1152 + 1024 + cz)*8 + jz] = (__bf16)0.f;
  }
  if (kb == 0 && t < 32){
    int hh = t >> 3, ii = t & 7;
    float b = 0.f;
    for (int c = 0; c < 64; c++) b += bq[hh*64 + c]*sWe2[ii*256 + hh*64 + c];
    bcat[1024 + t] = 0.125f*b;
  }
}

__global__ void k_prep(WPtrs wp, __bf16* __restrict__ W0cat, __bf16* __restrict__ W1cat,
                       float* __restrict__ bcat0, float* __restrict__ bcat1,
                       const float* __restrict__ Wq0, const float* __restrict__ bq0,
                       const float* __restrict__ We0,
                       const float* __restrict__ Wq1, const float* __restrict__ bq1,
                       const float* __restrict__ We1,
                       const float* __restrict__ eW1, const float* __restrict__ eb1,
                       const float* __restrict__ eW2, const float* __restrict__ eg1,
                       const float* __restrict__ eb2, const float* __restrict__ ebe1,
                       __bf16* __restrict__ Ecat){
  __shared__ float sWq[2048], sWe2[2048];
  const int b = blockIdx.x, t = threadIdx.x;
  if (b < 200){
    int gid = b*256 + t;
    if (gid < 16384){
      int mat = gid >> 12, v = gid & 4095;
      int colm = v & 255, q = v >> 8;
      int k0 = (q>>1)*16 + (q&1)*8;
      const float* W = wp.w[mat];
      bf16x8 vec;
      #pragma unroll
      for (int j = 0; j < 8; j++) vec[j] = (__bf16)W[(size_t)(k0+j)*256 + colm];
      *(bf16x8*)&W0cat[((size_t)q*1152 + mat*256 + colm)*8] = vec;
    } else if (gid < 49152){
      int g = gid - 16384;
      int mat = g >> 13, v = g & 8191;
      int colm = v & 255, q = v >> 8;
      int k0 = (q>>1)*16 + (q&1)*8;
      const float* W = wp.w[4+mat];
      bf16x8 vec;
      #pragma unroll
      for (int j = 0; j < 8; j++) vec[j] = (__bf16)W[(size_t)(k0+j)*256 + colm];
      *(bf16x8*)&W1cat[((size_t)q*1152 + mat*256 + colm)*8] = vec;
    } else if (gid < 51200){
      int g = gid - 49152;
      if (g < 1024) bcat0[g] = wp.b[g>>8][g&255];
      else { int h = g-1024; bcat1[h] = wp.b[4 + (h>>8)][h&255]; }
    }
  } else if (b < 216){
    mprep_body(Wq0, bq0, We0, W0cat, bcat0, b - 200, sWq, sWe2);
  } else if (b < 248){
    mprep_body(Wq1, bq1, We1, W1cat, bcat1, b - 216, sWq, sWe2);
  } else {
    int i = (b - 248)*256 + t;
    if (i >= 2816) return;
    bf16x8 v;
    if (i < 512){
      int r = i & 31, hh = (i>>5)&1, ks = (i>>6)&1, rt = i>>7;
      int feat = rt*32 + r, k0 = ks*16 + hh*8;
      #pragma unroll
      for (int j = 0; j < 8; j++){
        int k = k0 + j;
        float val = (k < 24) ? eW1[k*128 + feat] : ((k == 24) ? eb1[feat] : 0.f);
        v[j] = (__bf16)val;
      }
    } else {
      int m = i - 512;
      int r = m & 31, hh = (m>>5)&1, q = m>>6;
      int ks = q % 9, rt = q / 9;
      int feat = rt*32 + r, k0 = ks*16 + hh*8;
      #pragma unroll
      for (int j = 0; j < 8; j++){
        int k = k0 + j;
        float val;
        if (k < 128) val = eg1[k]*eW2[k*128 + feat];
        else if (k == 128){
          float a = eb2[feat];
          for (int kk = 0; kk < 128; kk++) a += ebe1[kk]*eW2[kk*128 + feat];
          val = a;
        } else val = 0.f;
        v[j] = (__bf16)val;
      }
    }
    *(bf16x8*)&Ecat[(size_t)i*8] = v;
  }
}

// ---------------- EmbedConv v7: edge-split (2 waves/window), 2 blocks/CU ----------------
__global__ __launch_bounds__(256, 1) void k_embed(
    const float* __restrict__ x, const float4* __restrict__ ea_csr,
    const int* __restrict__ csrc, const int* __restrict__ rowptr,
    const int* __restrict__ perm, const __bf16* __restrict__ Ecat,
    const float* __restrict__ g2, const float* __restrict__ be2,
    u16* __restrict__ h0b)
{
  __shared__ alignas(16) __bf16 sE[2816*8];   // 45 KB (reused post-loop as f32 exchange)
  __shared__ float sg2[128], sbe2[128];
  const int t = threadIdx.x;
  const int wv = t >> 6, ln = t & 63, hi = ln >> 5, c32 = ln & 31;

  #pragma unroll
  for (int k = 0; k < 11; k++){
    int base = k*256 + wv*64;
    gload16(Ecat + (size_t)(base + ln)*8, &sE[(size_t)base*8]);
  }
  if (t < 128){ sg2[t] = g2[t]; sbe2[t] = be2[t]; }
  asm volatile("s_waitcnt vmcnt(0)" ::: "memory");
  __syncthreads();

  const int win  = blockIdx.x + (wv >> 1)*512;
  const int half = wv & 1;
  const int d    = perm[win*32 + c32];
  const int rp   = rowptr[d];
  const int deg  = rowptr[d+1] - rp;
  int md = deg;
  #pragma unroll
  for (int m = 1; m < 32; m <<= 1) md = max(md, __shfl_xor(md, m, 32));

  f32x16 hacc[4] = {};

  bool vc = half < deg;
  int p0 = vc ? (rp + half) : rp;
  int sc = csrc[p0];
  float4 xa = *(const float4*)&x[(size_t)sc*16 + hi*8];
  float4 xb = *(const float4*)&x[(size_t)sc*16 + hi*8 + 4];
  float4 ga = ea_csr[(size_t)p0*2];
  float4 gb = ea_csr[(size_t)p0*2 + 1];

  for (int j = half; j < md; j += 2){
    const float vm = vc ? 1.f : 0.f;
    bf16x8 b1f0, b1f1;
    {
      float xv[8]; *(float4*)&xv[0] = xa; *(float4*)&xv[4] = xb;
      #pragma unroll
      for (int q = 0; q < 8; q++) b1f0[q] = (__bf16)(xv[q]*vm);
      float evv[8]; *(float4*)&evv[0] = ga; *(float4*)&evv[4] = gb;
      #pragma unroll
      for (int q = 0; q < 8; q++)
        b1f1[q] = (__bf16)(hi ? ((q == 0) ? vm : 0.f) : evv[q]*vm);
    }

    bool vn = (j + 2) < deg;
    int pn = vn ? (rp + j + 2) : rp;
    int sn = csrc[pn];
    float4 xan = *(const float4*)&x[(size_t)sn*16 + hi*8];
    float4 xbn = *(const float4*)&x[(size_t)sn*16 + hi*8 + 4];
    float4 gan = ea_csr[(size_t)pn*2];
    float4 gbn = ea_csr[(size_t)pn*2 + 1];

    f32x16 a1[4] = {};
    #pragma unroll
    for (int ks = 0; ks < 2; ks++)
      #pragma unroll
      for (int rt = 0; rt < 4; rt++){
        bf16x8 af = *(const bf16x8*)&sE[((((rt*2 + ks)*2 + hi)*32) + c32)*8];
        a1[rt] = __builtin_amdgcn_mfma_f32_32x32x16_bf16(af, ks ? b1f1 : b1f0, a1[rt], 0, 0, 0);
      }

    {
      float s1 = 0.f, s2 = 0.f;
      #pragma unroll
      for (int rt = 0; rt < 4; rt++)
        #pragma unroll
        for (int rg = 0; rg < 16; rg++){
          float v = fmaxf(a1[rt][rg], 0.f);
          a1[rt][rg] = v; s1 += v; s2 += v*v;
        }
      s1 += __shfl_xor(s1, 32, 64);
      s2 += __shfl_xor(s2, 32, 64);
      float mean = s1*(1.f/128.f);
      float rs = rsqrtf(s2*(1.f/128.f) - mean*mean + 1e-5f);
      #pragma unroll
      for (int rt = 0; rt < 4; rt++)
        #pragma unroll
        for (int rg = 0; rg < 16; rg++)
          a1[rt][rg] = (a1[rt][rg] - mean)*rs;
    }

    f32x16 a2[4] = {};
    #pragma unroll
    for (int ks = 0; ks < 8; ks++){
      const int tt = ks >> 1, bb = (ks & 1)*8;
      float snd[4], rcv[4];
      #pragma unroll
      for (int q = 0; q < 4; q++)
        snd[q] = hi ? a1[tt][bb + q] : a1[tt][bb + 4 + q];
      #pragma unroll
      for (int q = 0; q < 4; q++)
        rcv[q] = __shfl_xor(snd[q], 32, 64);
      bf16x8 bf;
      #pragma unroll
      for (int q = 0; q < 4; q++){
        float lo = hi ? rcv[q] : a1[tt][bb + q];
        float hh = hi ? a1[tt][bb + 4 + q] : rcv[q];
        bf[q]     = (__bf16)lo;
        bf[4 + q] = (__bf16)hh;
      }
      #pragma unroll
      for (int rt = 0; rt < 4; rt++){
        bf16x8 af = *(const bf16x8*)&sE[(512 + (((rt*9 + ks)*2 + hi)*32) + c32)*8];
        a2[rt] = __builtin_amdgcn_mfma_f32_32x32x16_bf16(af, bf, a2[rt], 0, 0, 0);
      }
    }
    {
      bf16x8 bf;
      #pragma unroll
      for (int q = 0; q < 8; q++)
        bf[q] = (__bf16)((!hi && q == 0) ? vm : 0.f);
      #pragma unroll
      for (int rt = 0; rt < 4; rt++){
        bf16x8 af = *(const bf16x8*)&sE[(512 + (((rt*9 + 8)*2 + hi)*32) + c32)*8];
        a2[rt] = __builtin_amdgcn_mfma_f32_32x32x16_bf16(af, bf, a2[rt], 0, 0, 0);
      }
    }

    {
      float s1 = 0.f, s2 = 0.f;
      #pragma unroll
      for (int rt = 0; rt < 4; rt++)
        #pragma unroll
        for (int rg = 0; rg < 16; rg++){
          float v = fmaxf(a2[rt][rg], 0.f);
          a2[rt][rg] = v; s1 += v; s2 += v*v;
        }
      s1 += __shfl_xor(s1, 32, 64);
      s2 += __shfl_xor(s2, 32, 64);
      float mean = s1*(1.f/128.f);
      float rs = rsqrtf(s2*(1.f/128.f) - mean*mean + 1e-5f);
      #pragma unroll
      for (int rt = 0; rt < 4; rt++)
        #pragma unroll
        for (int rg = 0; rg < 16; rg++)
          hacc[rt][rg] += (a2[rt][rg] - mean)*rs;
    }

    vc = vn;
    xa = xan; xb = xbn; ga = gan; gb = gbn;
  }

  __syncthreads();
  float* xch = (float*)sE;
  const int wbase = (wv >> 1)*(64*65);
  if (!half){
    #pragma unroll
    for (int rt = 0; rt < 4; rt++)
      #pragma unroll
      for (int rg = 0; rg < 16; rg++)
        xch[wbase + (rt*16 + rg)*65 + ln] = hacc[rt][rg];
  }
  __syncthreads();
  if (half){
    const float dd = (float)deg;
    #pragma unroll
    for (int rt = 0; rt < 4; rt++){
      #pragma unroll
      for (int rg = 0; rg < 16; rg++)
        hacc[rt][rg] += xch[wbase + (rt*16 + rg)*65 + ln];
      #pragma unroll
      for (int q = 0; q < 4; q++){
        int fb = rt*32 + 8*q + 4*hi;
        ushort4 o;
        o.x = f2bf(sg2[fb+0]*hacc[rt][q*4+0] + dd*sbe2[fb+0]);
        o.y = f2bf(sg2[fb+1]*hacc[rt][q*4+1] + dd*sbe2[fb+1]);
        o.z = f2bf(sg2[fb+2]*hacc[rt][q*4+2] + dd*sbe2[fb+2]);
        o.w = f2bf(sg2[fb+3]*hacc[rt][q*4+3] + dd*sbe2[fb+3]);
        *(ushort4*)&h0b[(size_t)d*128 + fb] = o;
      }
    }
  }
}

// ---------------- qkvs GEMM v4: single-buffer, 9 col-tiles (q,k,v,s,wqe), fused kv ----------------
template<int K>
__global__ __launch_bounds__(256) void k_qkvs2(const u16* __restrict__ A,
    const __bf16* __restrict__ Wcat, const float* __restrict__ bcat,
    u16* __restrict__ qo, u16* __restrict__ kvb, u16* __restrict__ so,
    u16* __restrict__ wqe)
{
  __shared__ alignas(16) __bf16 sA[1024*8];   // 16 KB
  __shared__ alignas(16) __bf16 sB[1024*8];   // 16 KB
  const int t = threadIdx.x;
  const int swz = (blockIdx.x & 7)*288 + (blockIdx.x >> 3);   // 2304 blocks, 8 XCDs
  const int r0 = (swz / 9)*128, c0 = (swz % 9)*128;
  const int wv = t >> 6, ln = t & 63, hi = ln >> 5, c32 = ln & 31;
  const int wr = wv >> 1, wc = wv & 1;

  f32x16 acc[2][2] = {};
  for (int kc = 0; kc < K/64; kc++){
    __syncthreads();
    #pragma unroll
    for (int ii = 0; ii < 4; ii++){
      int v = ii*256 + wv*64 + ln;
      int r = v & 31, hh = (v>>5)&1, ks = (v>>6)&3, rt = v>>8;
      gload16(A + (size_t)(r0 + rt*32 + r)*K + kc*64 + ks*16 + hh*8,
              &sA[(size_t)(ii*256 + wv*64)*8]);
    }
    #pragma unroll
    for (int ii = 0; ii < 4; ii++){
      int v = ii*256 + wv*64 + ln;
      int col = v & 127, q = v >> 7;
      gload16(Wcat + ((size_t)(kc*8 + q)*1152 + c0 + col)*8,
              &sB[(size_t)(ii*256 + wv*64)*8]);
    }
    asm volatile("s_waitcnt vmcnt(0)" ::: "memory");
    __syncthreads();
    #pragma unroll
    for (int ks = 0; ks < 4; ks++){
      bf16x8 af0 = *(const bf16x8*)&sA[((((wr*2+0)*4 + ks)*2 + hi)*32 + c32)*8];
      bf16x8 af1 = *(const bf16x8*)&sA[((((wr*2+1)*4 + ks)*2 + hi)*32 + c32)*8];
      bf16x8 bf0 = *(const bf16x8*)&sB[(((ks*2 + hi)*128) + wc*64 + c32)*8];
      bf16x8 bf1 = *(const bf16x8*)&sB[(((ks*2 + hi)*128) + wc*64 + 32 + c32)*8];
      acc[0][0] = __builtin_amdgcn_mfma_f32_32x32x16_bf16(af0, bf0, acc[0][0], 0, 0, 0);
      acc[0][1] = __builtin_amdgcn_mfma_f32_32x32x16_bf16(af0, bf1, acc[0][1], 0, 0, 0);
      acc[1][0] = __builtin_amdgcn_mfma_f32_32x32x16_bf16(af1, bf0, acc[1][0], 0, 0, 0);
      acc[1][1] = __builtin_amdgcn_mfma_f32_32x32x16_bf16(af1, bf1, acc[1][1], 0, 0, 0);
    }
  }

  const int tile = c0 >> 7;
  u16* omp; int rstride; int vadd = -1; bool wq8 = false;
  if (tile < 2)      { omp = qo;  rstride = 256; }
  else if (tile < 4) { omp = kvb; rstride = 512; vadd = 0; }
  else if (tile < 6) { omp = kvb; rstride = 512; vadd = 4; }
  else if (tile < 8) { omp = so;  rstride = 256; }
  else               { omp = wqe; rstride = 32; wq8 = true; }
  const int cb = c0 & 255;
  #pragma unroll
  for (int ci = 0; ci < 2; ci++){
    int colm = (wq8 ? 0 : cb) + wc*64 + ci*32 + c32;
    int coff = (vadd >= 0) ? (((colm >> 2) << 3) + vadd + (colm & 3)) : colm;
    float bb = bcat[c0 + wc*64 + ci*32 + c32];
    if (wq8 && colm >= 32) continue;
    #pragma unroll
    for (int ri = 0; ri < 2; ri++){
      #pragma unroll
      for (int rg = 0; rg < 16; rg++){
        int row = r0 + (wr*2 + ri)*32 + (rg&3) + 8*(rg>>2) + 4*hi;
        omp[(size_t)row*rstride + coff] = f2bf(acc[ri][ci][rg] + bb);
      }
    }
  }
}

// ---------------- TransformerConv attention v5 (reverted): fused kv, 4-deep, precomputed wqe ----------------
template<bool OBF>
__global__ __launch_bounds__(256) void k_attn(
    const int* __restrict__ csrc, const int* __restrict__ rowptr,
    const float4* __restrict__ ea_csr, const float* __restrict__ We,
    const u16* __restrict__ qb, const u16* __restrict__ kvb,
    const u16* __restrict__ skb, const u16* __restrict__ wqe,
    void* __restrict__ outp)
{
  __shared__ float sWe[8*256];
  const int t = threadIdx.x;
  for (int i = t; i < 2048; i += 256) sWe[i] = We[i];
  __syncthreads();

  const float* eaf = (const float*)ea_csr;
  const int wv = t >> 6, ln = t & 63;
  const int f = (ln >> 4)*64 + (ln & 15)*4;
  const int kvo = ((ln >> 4)*16 + (ln & 15))*8;
  const int iown = ln & 7;
  const int gbase = ln & ~15;
  const int gw = blockIdx.x*4 + wv, nW = gridDim.x*4;

#define ATT_PRE(RX, EX, jj) do{                                            \
      int sj_ = ((jj) < 64) ? __shfl(sidx, (jj), 64) : csrc[rp + (jj)];    \
      RX = *(const int4*)&kvb[(size_t)sj_*512 + kvo];                      \
      EX = eaf[(size_t)(rp + (jj))*8 + iown];                              \
    }while(0)

#define ATT_STEP(RX, EX) do{                                               \
      float kx0 = bf2f((u16)(RX.x & 0xffff)), kx1 = bf2f((u16)(((u32)RX.x)>>16)); \
      float kx2 = bf2f((u16)(RX.y & 0xffff)), kx3 = bf2f((u16)(((u32)RX.y)>>16)); \
      float vx0 = bf2f((u16)(RX.z & 0xffff)), vx1 = bf2f((u16)(((u32)RX.z)>>16)); \
      float vx2 = bf2f((u16)(RX.w & 0xffff)), vx3 = bf2f((u16)(((u32)RX.w)>>16)); \
      float spp = qv.x*kx0 + qv.y*kx1 + qv.z*kx2 + qv.w*kx3 + EX*wqsel;    \
      spp += __shfl_xor(spp, 1, 64); spp += __shfl_xor(spp, 2, 64);        \
      spp += __shfl_xor(spp, 4, 64); spp += __shfl_xor(spp, 8, 64);        \
      float nm = fmaxf(m, spp);                                            \
      float sc_ = __expf(m - nm);                                          \
      float pp = __expf(spp - nm);                                         \
      l = l*sc_ + pp;                                                      \
      o0 = o0*sc_ + pp*vx0; o1 = o1*sc_ + pp*vx1;                          \
      o2 = o2*sc_ + pp*vx2; o3 = o3*sc_ + pp*vx3;                          \
      weal = weal*sc_ + pp*EX;                                             \
      m = nm;                                                              \
    }while(0)

  for (int d = gw; d < NN; d += nW){
    const int rp = rowptr[d];
    const int dg = rowptr[d+1] - rp;
    float4 qv = ldbf4(qb + (size_t)d*256 + f);
    qv.x *= 0.125f; qv.y *= 0.125f; qv.z *= 0.125f; qv.w *= 0.125f;
    float4 sv = ldbf4(skb + (size_t)d*256 + f);

    float wqsel = ((ln & 15) < 8)
                ? bf2f(wqe[(size_t)d*32 + (ln >> 4)*8 + (ln & 7)]) : 0.f;

    float m = -INFINITY, l = 0.f, o0 = 0, o1 = 0, o2 = 0, o3 = 0, weal = 0.f;

    if (dg > 0){
      int sidx = (ln < dg) ? csrc[rp + ln] : 0;
      int4 rA, rB, rC, rD; float eA, eB, eC, eD;
      ATT_PRE(rA, eA, 0);
      if (dg > 1) ATT_PRE(rB, eB, 1);
      if (dg > 2) ATT_PRE(rC, eC, 2);
      if (dg > 3) ATT_PRE(rD, eD, 3);

      int j = 0;
      while (j < dg){
        ATT_STEP(rA, eA); if (j + 4 < dg) ATT_PRE(rA, eA, j + 4); if (++j >= dg) break;
        ATT_STEP(rB, eB); if (j + 4 < dg) ATT_PRE(rB, eB, j + 4); if (++j >= dg) break;
        ATT_STEP(rC, eC); if (j + 4 < dg) ATT_PRE(rC, eC, j + 4); if (++j >= dg) break;
        ATT_STEP(rD, eD); if (j + 4 < dg) ATT_PRE(rD, eD, j + 4); ++j;
      }
    }

    float il = (l > 0.f) ? 1.f/l : 0.f;
    float ec0 = 0, ec1 = 0, ec2 = 0, ec3 = 0;
    #pragma unroll
    for (int i = 0; i < 8; i++){
      float wi = __shfl(weal, gbase + i, 64);
      float4 w = *(const float4*)&sWe[i*256 + f];
      ec0 += wi*w.x; ec1 += wi*w.y; ec2 += wi*w.z; ec3 += wi*w.w;
    }
    o0 = fmaxf((o0 + ec0)*il + sv.x, 0.f);
    o1 = fmaxf((o1 + ec1)*il + sv.y, 0.f);
    o2 = fmaxf((o2 + ec2)*il + sv.z, 0.f);
    o3 = fmaxf((o3 + ec3)*il + sv.w, 0.f);
    if constexpr (OBF){
      ushort4 o; o.x = f2bf(o0); o.y = f2bf(o1); o.z = f2bf(o2); o.w = f2bf(o3);
      *(ushort4*)((u16*)outp + (size_t)d*256 + f) = o;
    } else {
      *(float4*)((float*)outp + (size_t)d*256 + f) = make_float4(o0, o1, o2, o3);
    }
  }
#undef ATT_PRE
#undef ATT_STEP
}

extern "C" void kernel_launch(void* const* d_in, const int* in_sizes, int n_in,
                              void* d_out, int out_size, void* d_ws, size_t ws_size,
                              hipStream_t stream)
{
  (void)in_sizes; (void)n_in; (void)out_size; (void)ws_size;
  const float* x   = (const float*)d_in[0];
  const int*   ei  = (const int*)  d_in[1];
  const float* ea  = (const float*)d_in[2];
  const float* eW1 = (const float*)d_in[3];
  const float* eb1 = (const float*)d_in[4];
  const float* eg1 = (const float*)d_in[5];
  const float* ebe1= (const float*)d_in[6];
  const float* eW2 = (const float*)d_in[7];
  const float* eb2 = (const float*)d_in[8];
  const float* eg2 = (const float*)d_in[9];
  const float* ebe2= (const float*)d_in[10];

  char* ws = (char*)d_ws;
  const size_t MB = (size_t)1 << 20;
  const size_t KB = (size_t)1 << 10;
  int*   deg    = (int*)(ws);
  int*   cursor = (int*)(ws + 128*KB);
  int*   rowptr = (int*)(ws + 256*KB);
  int*   bsum   = (int*)(ws + 400*KB);
  int*   boff   = (int*)(ws + 402*KB);
  int*   ghist  = (int*)(ws + 408*KB);
  int*   gcur   = (int*)(ws + 412*KB);
  int*   goff   = (int*)(ws + 416*KB);
  int*   perm   = (int*)(ws + 512*KB);
  int*   csrc   = (int*)(ws + 1*MB);
  float4* ea_csr= (float4*)(ws + 4*MB);
  u16*   qb     = (u16*)(ws + 20*MB);
  u16*   kvb    = (u16*)(ws + 36*MB);
  u16*   skb    = (u16*)(ws + 68*MB);
  u16*   h1     = (u16*)(ws + 84*MB);
  u16*   h0b    = (u16*)(ws + 100*MB);
  __bf16* W0cat = (__bf16*)(ws + 108*MB);
  __bf16* W1cat = (__bf16*)(ws + 109*MB);
  float* bcat0  = (float*)(ws + 110*MB);
  float* bcat1  = (float*)(ws + 110*MB + 64*KB);
  __bf16* Ecat  = (__bf16*)(ws + 111*MB);
  u16*   wqeb   = (u16*)(ws + 112*MB);

  hipMemsetAsync(ws, 0, 420*KB, stream);

  WPtrs wp;
  wp.w[0] = (const float*)d_in[11]; wp.b[0] = (const float*)d_in[12];
  wp.w[1] = (const float*)d_in[13]; wp.b[1] = (const float*)d_in[14];
  wp.w[2] = (const float*)d_in[15]; wp.b[2] = (const float*)d_in[16];
  wp.w[3] = (const float*)d_in[18]; wp.b[3] = (const float*)d_in[19];
  wp.w[4] = (const float*)d_in[20]; wp.b[4] = (const float*)d_in[21];
  wp.w[5] = (const float*)d_in[22]; wp.b[5] = (const float*)d_in[23];
  wp.w[6] = (const float*)d_in[24]; wp.b[6] = (const float*)d_in[25];
  wp.w[7] = (const float*)d_in[27]; wp.b[7] = (const float*)d_in[28];

  k_deg        <<<NE/256, 256, 0, stream>>>(ei, deg);
  k_prep       <<<259,    256, 0, stream>>>(wp, W0cat, W1cat, bcat0, bcat1,
                  (const float*)d_in[11], (const float*)d_in[12], (const float*)d_in[17],
                  (const float*)d_in[20], (const float*)d_in[21], (const float*)d_in[26],
                  eW1, eb1, eW2, eg1, eb2, ebe1, Ecat);
  k_scan1hist  <<<256, 256, 0, stream>>>(deg, rowptr, bsum, ghist);
  k_scan2hoff  <<<2,   128, 0, stream>>>(bsum, boff, ghist, goff);
  k_scan3scatter<<<256,256, 0, stream>>>(rowptr, boff, deg, goff, gcur, perm);
  k_fill       <<<NE/256, 256, 0, stream>>>(ei, rowptr, cursor, ea, csrc, ea_csr);

  k_embed<<<512, 256, 0, stream>>>(x, ea_csr, csrc, rowptr, perm, Ecat, eg2, ebe2, h0b);

  // layer 0 (K = 128)
  k_qkvs2<128><<<2304, 256, 0, stream>>>(h0b, W0cat, bcat0, qb, kvb, skb, wqeb);
  k_attn<true><<<NN/4, 256, 0, stream>>>(csrc, rowptr, ea_csr, (const float*)d_in[17],
                                         qb, kvb, skb, wqeb, (void*)h1);
  // layer 1 (K = 256)
  k_qkvs2<256><<<2304, 256, 0, stream>>>(h1, W1cat, bcat1, qb, kvb, skb, wqeb);
  k_attn<false><<<NN/4, 256, 0, stream>>>(csrc, rowptr, ea_csr, (const float*)d_in[26],
                                          qb, kvb, skb, wqeb, d_out);
}